// Round 2
// baseline (433.986 us; speedup 1.0000x reference)
//
#include <hip/hip_runtime.h>
#include <hip/hip_cooperative_groups.h>
#include <math.h>

namespace cg = cooperative_groups;

#define Bb 2
#define Nn 2048
#define Hh 256
#define NH 8
#define HD 32
#define NEDGE 65536
#define LN_EPS 1e-5f
#define MW 64          // mask words per row = N/32
#define LDA2 72

typedef __bf16 bf16_t;
typedef bf16_t bf16x8 __attribute__((ext_vector_type(8)));
typedef bf16_t bf16x4 __attribute__((ext_vector_type(4)));
typedef float f32x4 __attribute__((ext_vector_type(4)));

// ===========================================================================
// Fused cooperative kernel. Phases separated by grid.sync():
//   P0: zero mask
//   P1: QKV GEMM (units 0..767) || build mask from edges (units 768..1023)
//   P2: sparse attention, grid-stride over 2048 rows (both batches per row)
//   P3: out = LayerNorm(attn @ Wo^T + x), 256 tile-units of 16 rows
// LDS: single 39168 B union (out_ln is the max phase) -> 4 blocks/CU.
// __launch_bounds__(256,4): <=128 VGPR so 1024 blocks are co-resident.
// ===========================================================================
__global__ __launch_bounds__(256, 4) void fused_kernel(
    const float* __restrict__ x, const int* __restrict__ ei,
    const float* __restrict__ Wq, const float* __restrict__ Wk, const float* __restrict__ Wv,
    const float* __restrict__ Wo, const float* __restrict__ gamma, const float* __restrict__ beta,
    float* __restrict__ Qb, bf16_t* __restrict__ Kb16, bf16_t* __restrict__ Vb16,
    float* __restrict__ attnb, unsigned int* __restrict__ mask, float* __restrict__ out)
{
    __shared__ __align__(16) char smembuf[39168];
    cg::grid_group grid = cg::this_grid();
    const int t = threadIdx.x;
    const int bid = blockIdx.x;
    const int g = gridDim.x;
    const int lane = t & 63, w = t >> 6;
    const int ml = lane & 15, quad = lane >> 4;

    // ---------------- P0: zero the adjacency bitmask (512 KB) ----------------
    {
        uint4* m4 = (uint4*)mask;
        const uint4 z = make_uint4(0, 0, 0, 0);
        for (int idx = bid * 256 + t; idx < Nn * MW / 4; idx += g * 256)
            m4[idx] = z;
    }
    grid.sync();

    // ---------------- P1: QKV GEMM || mask build -----------------------------
    {
        bf16_t* As = (bf16_t*)smembuf;            // 64 x 72 bf16 = 9216 B
        bf16_t* Ws = (bf16_t*)(smembuf + 9216);   // 64 x 72 bf16
        const int wm = w & 1, wn = w >> 1;
        const int srow = t >> 3, scol = (t & 7) * 8;
        for (int u = bid; u < 1024; u += g) {
            if (u < 768) {
                // ---- one 64x64 GEMM tile ----
                int m0 = (u & 63) << 6;
                int ysel = u >> 6;
                int wsel = ysel >> 2;
                const float* W = (wsel == 0) ? Wq : ((wsel == 1) ? Wk : Wv);
                int n0 = (ysel & 3) << 6;
                f32x4 acc[2][2];
                f32x4 zero = {0.f, 0.f, 0.f, 0.f};
                acc[0][0] = zero; acc[0][1] = zero; acc[1][0] = zero; acc[1][1] = zero;
                for (int k0 = 0; k0 < Hh; k0 += 64) {
                    float4 a[2][2], bwt[2][2];
                    #pragma unroll
                    for (int s = 0; s < 2; ++s) {
                        const float* ap = x + (size_t)(m0 + srow + s * 32) * Hh + k0 + scol;
                        a[s][0] = *(const float4*)ap;
                        a[s][1] = *(const float4*)(ap + 4);
                        const float* bp = W + (size_t)(n0 + srow + s * 32) * Hh + k0 + scol;
                        bwt[s][0] = *(const float4*)bp;
                        bwt[s][1] = *(const float4*)(bp + 4);
                    }
                    __syncthreads();
                    #pragma unroll
                    for (int s = 0; s < 2; ++s) {
                        bf16x8 av = {(bf16_t)a[s][0].x, (bf16_t)a[s][0].y, (bf16_t)a[s][0].z, (bf16_t)a[s][0].w,
                                     (bf16_t)a[s][1].x, (bf16_t)a[s][1].y, (bf16_t)a[s][1].z, (bf16_t)a[s][1].w};
                        bf16x8 bv = {(bf16_t)bwt[s][0].x, (bf16_t)bwt[s][0].y, (bf16_t)bwt[s][0].z, (bf16_t)bwt[s][0].w,
                                     (bf16_t)bwt[s][1].x, (bf16_t)bwt[s][1].y, (bf16_t)bwt[s][1].z, (bf16_t)bwt[s][1].w};
                        *(bf16x8*)&As[(srow + s * 32) * LDA2 + scol] = av;
                        *(bf16x8*)&Ws[(srow + s * 32) * LDA2 + scol] = bv;
                    }
                    __syncthreads();
                    #pragma unroll
                    for (int kk = 0; kk < 64; kk += 32) {
                        bf16x8 af[2], bfr[2];
                        #pragma unroll
                        for (int i2 = 0; i2 < 2; ++i2) {
                            af[i2]  = *(const bf16x8*)&As[(wm * 32 + i2 * 16 + ml) * LDA2 + kk + quad * 8];
                            bfr[i2] = *(const bf16x8*)&Ws[(wn * 32 + i2 * 16 + ml) * LDA2 + kk + quad * 8];
                        }
                        #pragma unroll
                        for (int i2 = 0; i2 < 2; ++i2)
                            #pragma unroll
                            for (int j2 = 0; j2 < 2; ++j2)
                                acc[i2][j2] = __builtin_amdgcn_mfma_f32_16x16x32_bf16(af[i2], bfr[j2], acc[i2][j2], 0, 0, 0);
                    }
                }
                bf16_t* Ob16 = (wsel == 1) ? Kb16 : Vb16;
                #pragma unroll
                for (int i2 = 0; i2 < 2; ++i2)
                    #pragma unroll
                    for (int j2 = 0; j2 < 2; ++j2)
                        #pragma unroll
                        for (int r = 0; r < 4; ++r) {
                            int mg = m0 + wm * 32 + i2 * 16 + quad * 4 + r;
                            int ng = n0 + wn * 32 + j2 * 16 + ml;
                            float v = acc[i2][j2][r];
                            if (wsel == 0) Qb[(size_t)mg * Hh + ng] = v;
                            else           Ob16[(size_t)mg * Hh + ng] = (bf16_t)v;
                        }
            } else {
                // ---- one chunk of 256 edges -> atomicOr into mask ----
                int e = (u - 768) * 256 + t;
                int src = ei[e];
                int dst = ei[NEDGE + e];
                atomicOr(&mask[src * MW + (dst >> 5)], 1u << (dst & 31));
            }
        }
    }
    __threadfence();
    grid.sync();

    // ---------------- P2: sparse attention ----------------------------------
    {
        unsigned short* nbr = (unsigned short*)smembuf;   // 4096 B
        float* qs      = (float*)(smembuf + 4096);        // [2][256]
        float* sraw    = (float*)(smembuf + 6144);        // [2][288]
        float* scw     = (float*)(smembuf + 8448);        // [2][256]
        float* alpha_l = (float*)(smembuf + 10496);       // [2][8]
        float* linv_l  = (float*)(smembuf + 10560);       // [2][8]
        float* obuf    = (float*)(smembuf + 10624);       // [4][256]
        int*   nn_sh   = (int*)(smembuf + 14720);
        const int h = t >> 5, dl = t & 31;
        const int hw = lane >> 3;
        const float scale = 0.17677669529663687f;  // 1/sqrt(32)

        for (int i = bid; i < Nn; i += g) {
            if (t < 64) {   // wave 0: extract dedup'd neighbor list from bitmask
                unsigned int bits = mask[i * MW + t];
                int cnt = __popc(bits);
                int incl = cnt;
                #pragma unroll
                for (int off = 1; off < 64; off <<= 1) {
                    int v = __shfl_up(incl, off, 64);
                    if (t >= off) incl += v;
                }
                int idx = incl - cnt;
                unsigned int bb = bits;
                while (bb) {
                    int bit = __ffs(bb) - 1;
                    nbr[idx++] = (unsigned short)(t * 32 + bit);
                    bb &= bb - 1;
                }
                if (t == 63) *nn_sh = incl;
            }
            qs[t]       = Qb[(size_t)i * Hh + t];
            qs[256 + t] = Qb[(size_t)(Nn + i) * Hh + t];
            __syncthreads();
            int nn = *nn_sh;

            float m_run[2] = {-1e30f, -1e30f};
            float l_run[2] = {0.f, 0.f};
            float o[2][4] = {{0.f, 0.f, 0.f, 0.f}, {0.f, 0.f, 0.f, 0.f}};
            int nch = (nn + 31) >> 5;
            for (int c = 0; c < nch; ++c) {
                int base = c << 5;
                int lim = min(32, nn - base);
                #pragma unroll
                for (int b = 0; b < 2; ++b) {
                    float4 qv = *(const float4*)&qs[b * 256 + (lane << 2)];
                    #pragma unroll
                    for (int s = 0; s < 8; ++s) {
                        int r = (s << 2) + w;
                        if (r < lim) {
                            int j = nbr[base + r];
                            bf16x4 kv = *(const bf16x4*)(Kb16 + (((size_t)((b << 11) + j)) << 8) + (lane << 2));
                            float p = fmaf((float)kv.x, qv.x, fmaf((float)kv.y, qv.y,
                                      fmaf((float)kv.z, qv.z, (float)kv.w * qv.w)));
                            p += __shfl_xor(p, 1, 64);
                            p += __shfl_xor(p, 2, 64);
                            p += __shfl_xor(p, 4, 64);
                            if ((lane & 7) == 0) sraw[b * 288 + r * 9 + (lane >> 3)] = p * scale;
                        }
                    }
                }
                __syncthreads();
                #pragma unroll
                for (int b = 0; b < 2; ++b) {
                    float s_val = (dl < lim) ? sraw[b * 288 + dl * 9 + h] : -1e30f;
                    float mc = s_val;
                    #pragma unroll
                    for (int m = 1; m < 32; m <<= 1) mc = fmaxf(mc, __shfl_xor(mc, m, 64));
                    float m_new = fmaxf(m_run[b], mc);
                    float wgt = __expf(s_val - m_new);
                    float sum = wgt;
                    #pragma unroll
                    for (int m = 1; m < 32; m <<= 1) sum += __shfl_xor(sum, m, 64);
                    float alpha = __expf(m_run[b] - m_new);
                    l_run[b] = l_run[b] * alpha + sum;
                    m_run[b] = m_new;
                    scw[b * 256 + t] = wgt;
                    if (dl == 0) alpha_l[b * 8 + h] = alpha;
                }
                __syncthreads();
                #pragma unroll
                for (int b = 0; b < 2; ++b) {
                    float av = alpha_l[b * 8 + hw];
                    o[b][0] *= av; o[b][1] *= av; o[b][2] *= av; o[b][3] *= av;
                    #pragma unroll
                    for (int s = 0; s < 8; ++s) {
                        int r = (s << 2) + w;
                        if (r < lim) {
                            int j = nbr[base + r];
                            float wg = scw[b * 256 + (hw << 5) + r];
                            bf16x4 vv = *(const bf16x4*)(Vb16 + (((size_t)((b << 11) + j)) << 8) + (lane << 2));
                            o[b][0] = fmaf(wg, (float)vv.x, o[b][0]);
                            o[b][1] = fmaf(wg, (float)vv.y, o[b][1]);
                            o[b][2] = fmaf(wg, (float)vv.z, o[b][2]);
                            o[b][3] = fmaf(wg, (float)vv.w, o[b][3]);
                        }
                    }
                }
            }
            if (dl == 0) {
                linv_l[h]     = (l_run[0] > 0.f) ? 1.f / l_run[0] : 0.f;
                linv_l[8 + h] = (l_run[1] > 0.f) ? 1.f / l_run[1] : 0.f;
            }
            #pragma unroll
            for (int b = 0; b < 2; ++b) {
                __syncthreads();   // b=0: linv visible; also protects obuf reuse
                obuf[w * 256 + (lane << 2) + 0] = o[b][0];
                obuf[w * 256 + (lane << 2) + 1] = o[b][1];
                obuf[w * 256 + (lane << 2) + 2] = o[b][2];
                obuf[w * 256 + (lane << 2) + 3] = o[b][3];
                __syncthreads();
                float val = obuf[t] + obuf[256 + t] + obuf[512 + t] + obuf[768 + t];
                attnb[(((size_t)((b << 11) + i)) << 8) + t] = val * linv_l[b * 8 + (t >> 5)];
            }
        }
    }
    __threadfence();
    grid.sync();

    // ---------------- P3: out = LayerNorm(attn @ Wo^T + x) -------------------
    {
        bf16_t* As = (bf16_t*)smembuf;             // 16 x 72 bf16 = 2304 B
        bf16_t* Ws = (bf16_t*)(smembuf + 2304);    // 256 x 72 bf16 = 36864 B
        float*  yb = (float*)(smembuf + 2304);     // 16 x 260 fp32, aliased after use
        const int arow = t >> 4, acol = (t & 15) * 4;
        const int wrow = t >> 3, wcol = (t & 7) * 8;
        for (int u = bid; u < (Bb * Nn) / 16; u += g) {
            int m0 = u * 16;
            f32x4 acc[4];
            f32x4 zero = {0.f, 0.f, 0.f, 0.f};
            acc[0] = zero; acc[1] = zero; acc[2] = zero; acc[3] = zero;
            for (int k0 = 0; k0 < Hh; k0 += 64) {
                float4 av = *(const float4*)(attnb + (size_t)(m0 + arow) * Hh + k0 + acol);
                float4 wva[8], wvb[8];
                #pragma unroll
                for (int s = 0; s < 8; ++s) {
                    const float* wp = Wo + (size_t)(wrow + s * 32) * Hh + k0 + wcol;
                    wva[s] = *(const float4*)wp;
                    wvb[s] = *(const float4*)(wp + 4);
                }
                __syncthreads();
                bf16x4 ac = {(bf16_t)av.x, (bf16_t)av.y, (bf16_t)av.z, (bf16_t)av.w};
                *(bf16x4*)&As[arow * LDA2 + acol] = ac;
                #pragma unroll
                for (int s = 0; s < 8; ++s) {
                    bf16x8 wv8 = {(bf16_t)wva[s].x, (bf16_t)wva[s].y, (bf16_t)wva[s].z, (bf16_t)wva[s].w,
                                  (bf16_t)wvb[s].x, (bf16_t)wvb[s].y, (bf16_t)wvb[s].z, (bf16_t)wvb[s].w};
                    *(bf16x8*)&Ws[(wrow + s * 32) * LDA2 + wcol] = wv8;
                }
                __syncthreads();
                #pragma unroll
                for (int kk = 0; kk < 64; kk += 32) {
                    bf16x8 af = *(const bf16x8*)&As[ml * LDA2 + kk + quad * 8];
                    #pragma unroll
                    for (int ct = 0; ct < 4; ++ct) {
                        bf16x8 bfr = *(const bf16x8*)&Ws[(w * 64 + ct * 16 + ml) * LDA2 + kk + quad * 8];
                        acc[ct] = __builtin_amdgcn_mfma_f32_16x16x32_bf16(af, bfr, acc[ct], 0, 0, 0);
                    }
                }
            }
            __syncthreads();   // all Ws reads done before aliasing as yb
            #pragma unroll
            for (int ct = 0; ct < 4; ++ct)
                #pragma unroll
                for (int r = 0; r < 4; ++r) {
                    int row = quad * 4 + r;
                    int col = w * 64 + ct * 16 + ml;
                    yb[row * 260 + col] = acc[ct][r] + x[(size_t)(m0 + row) * Hh + col];
                }
            __syncthreads();
            for (int rr = 0; rr < 4; ++rr) {
                int row = w * 4 + rr;
                float4 v = *(const float4*)&yb[row * 260 + lane * 4];
                float sum = v.x + v.y + v.z + v.w;
                #pragma unroll
                for (int m = 1; m < 64; m <<= 1) sum += __shfl_xor(sum, m, 64);
                float mu = sum * (1.f / Hh);
                float4 d = {v.x - mu, v.y - mu, v.z - mu, v.w - mu};
                float ss = d.x * d.x + d.y * d.y + d.z * d.z + d.w * d.w;
                #pragma unroll
                for (int m = 1; m < 64; m <<= 1) ss += __shfl_xor(ss, m, 64);
                float r = rsqrtf(ss * (1.f / Hh) + LN_EPS);
                float4 gmv = *(const float4*)(gamma + lane * 4);
                float4 btv = *(const float4*)(beta + lane * 4);
                float4 ov = {d.x * r * gmv.x + btv.x, d.y * r * gmv.y + btv.y,
                             d.z * r * gmv.z + btv.z, d.w * r * gmv.w + btv.w};
                *(float4*)(out + (size_t)(m0 + row) * Hh + lane * 4) = ov;
            }
            __syncthreads();   // protect Ws/yb reuse on next grid-stride unit
        }
    }
}

// ===========================================================================
// Fallback path (round-1 kernels) if cooperative launch is unavailable.
// ===========================================================================
__global__ void build_mask_kernel(const int* __restrict__ ei, unsigned int* __restrict__ mask) {
    int e = blockIdx.x * blockDim.x + threadIdx.x;
    if (e >= NEDGE) return;
    int src = ei[e];
    int dst = ei[NEDGE + e];
    atomicOr(&mask[src * MW + (dst >> 5)], 1u << (dst & 31));
}

__global__ __launch_bounds__(256) void qkv_gemm3_kernel(
    const float* __restrict__ x,
    const float* __restrict__ Wq, const float* __restrict__ Wk, const float* __restrict__ Wv,
    float* __restrict__ Qb, bf16_t* __restrict__ Kb16, bf16_t* __restrict__ Vb16)
{
    __shared__ bf16_t As[64 * LDA2];
    __shared__ bf16_t Ws[64 * LDA2];
    int t = threadIdx.x;
    int lane = t & 63, w = t >> 6;
    int wm = w & 1, wn = w >> 1;
    int ml = lane & 15, quad = lane >> 4;
    int m0 = blockIdx.x * 64;
    int wsel = blockIdx.y >> 2;
    const float* W = (wsel == 0) ? Wq : ((wsel == 1) ? Wk : Wv);
    int n0 = (blockIdx.y & 3) * 64;
    int srow = t >> 3;
    int scol = (t & 7) * 8;
    f32x4 acc[2][2];
    f32x4 zero = {0.f, 0.f, 0.f, 0.f};
    acc[0][0] = zero; acc[0][1] = zero; acc[1][0] = zero; acc[1][1] = zero;

    for (int k0 = 0; k0 < Hh; k0 += 64) {
        float4 a[2][2], bwt[2][2];
        #pragma unroll
        for (int s = 0; s < 2; ++s) {
            const float* ap = x + (size_t)(m0 + srow + s * 32) * Hh + k0 + scol;
            a[s][0] = *(const float4*)ap;
            a[s][1] = *(const float4*)(ap + 4);
            const float* bp = W + (size_t)(n0 + srow + s * 32) * Hh + k0 + scol;
            bwt[s][0] = *(const float4*)bp;
            bwt[s][1] = *(const float4*)(bp + 4);
        }
        __syncthreads();
        #pragma unroll
        for (int s = 0; s < 2; ++s) {
            bf16x8 av = {(bf16_t)a[s][0].x, (bf16_t)a[s][0].y, (bf16_t)a[s][0].z, (bf16_t)a[s][0].w,
                         (bf16_t)a[s][1].x, (bf16_t)a[s][1].y, (bf16_t)a[s][1].z, (bf16_t)a[s][1].w};
            bf16x8 bv = {(bf16_t)bwt[s][0].x, (bf16_t)bwt[s][0].y, (bf16_t)bwt[s][0].z, (bf16_t)bwt[s][0].w,
                         (bf16_t)bwt[s][1].x, (bf16_t)bwt[s][1].y, (bf16_t)bwt[s][1].z, (bf16_t)bwt[s][1].w};
            *(bf16x8*)&As[(srow + s * 32) * LDA2 + scol] = av;
            *(bf16x8*)&Ws[(srow + s * 32) * LDA2 + scol] = bv;
        }
        __syncthreads();
        #pragma unroll
        for (int kk = 0; kk < 64; kk += 32) {
            bf16x8 af[2], bfr[2];
            #pragma unroll
            for (int i = 0; i < 2; ++i) {
                af[i]  = *(const bf16x8*)&As[(wm * 32 + i * 16 + ml) * LDA2 + kk + quad * 8];
                bfr[i] = *(const bf16x8*)&Ws[(wn * 32 + i * 16 + ml) * LDA2 + kk + quad * 8];
            }
            #pragma unroll
            for (int i = 0; i < 2; ++i)
                #pragma unroll
                for (int j = 0; j < 2; ++j)
                    acc[i][j] = __builtin_amdgcn_mfma_f32_16x16x32_bf16(af[i], bfr[j], acc[i][j], 0, 0, 0);
        }
    }
    bf16_t* Ob16 = (wsel == 1) ? Kb16 : Vb16;
    #pragma unroll
    for (int i = 0; i < 2; ++i)
        #pragma unroll
        for (int j = 0; j < 2; ++j)
            #pragma unroll
            for (int r = 0; r < 4; ++r) {
                int mg = m0 + wm * 32 + i * 16 + quad * 4 + r;
                int ng = n0 + wn * 32 + j * 16 + ml;
                float v = acc[i][j][r];
                if (wsel == 0) Qb[(size_t)mg * Hh + ng] = v;
                else           Ob16[(size_t)mg * Hh + ng] = (bf16_t)v;
            }
}

__global__ __launch_bounds__(256) void attn6_kernel(
    const float* __restrict__ Qb, const bf16_t* __restrict__ Kb16, const bf16_t* __restrict__ Vb16,
    const unsigned int* __restrict__ mask, float* __restrict__ attnb)
{
    __shared__ unsigned short nbr[Nn];
    __shared__ float qs[2][Hh];
    __shared__ float sraw[2][32 * 9];
    __shared__ float scw[2][Hh];
    __shared__ float alpha_l[2][NH];
    __shared__ float linv_l[2][NH];
    __shared__ float obuf[4][Hh];
    __shared__ int nn_sh;
    int i = blockIdx.x;
    int t = threadIdx.x;
    int h = t >> 5, dl = t & 31;
    int w = t >> 6, lane = t & 63;
    int hw = lane >> 3;

    if (t < 64) {
        unsigned int bits = mask[i * MW + t];
        int cnt = __popc(bits);
        int incl = cnt;
        #pragma unroll
        for (int off = 1; off < 64; off <<= 1) {
            int v = __shfl_up(incl, off, 64);
            if (t >= off) incl += v;
        }
        int idx = incl - cnt;
        unsigned int bb = bits;
        while (bb) {
            int bit = __ffs(bb) - 1;
            nbr[idx++] = (unsigned short)(t * 32 + bit);
            bb &= bb - 1;
        }
        if (t == 63) nn_sh = incl;
    }
    qs[0][t] = Qb[(size_t)i * Hh + t];
    qs[1][t] = Qb[(size_t)(Nn + i) * Hh + t];
    __syncthreads();
    int nn = nn_sh;

    float m_run[2] = {-1e30f, -1e30f};
    float l_run[2] = {0.f, 0.f};
    float o[2][4] = {{0.f, 0.f, 0.f, 0.f}, {0.f, 0.f, 0.f, 0.f}};
    const float scale = 0.17677669529663687f;
    int nch = (nn + 31) >> 5;
    for (int c = 0; c < nch; ++c) {
        int base = c << 5;
        int lim = min(32, nn - base);
        #pragma unroll
        for (int b = 0; b < 2; ++b) {
            float4 qv = *(const float4*)&qs[b][lane << 2];
            #pragma unroll
            for (int s = 0; s < 8; ++s) {
                int r = (s << 2) + w;
                if (r < lim) {
                    int j = nbr[base + r];
                    bf16x4 kv = *(const bf16x4*)(Kb16 + (((size_t)((b << 11) + j)) << 8) + (lane << 2));
                    float p = fmaf((float)kv.x, qv.x, fmaf((float)kv.y, qv.y,
                              fmaf((float)kv.z, qv.z, (float)kv.w * qv.w)));
                    p += __shfl_xor(p, 1, 64);
                    p += __shfl_xor(p, 2, 64);
                    p += __shfl_xor(p, 4, 64);
                    if ((lane & 7) == 0) sraw[b][r * 9 + (lane >> 3)] = p * scale;
                }
            }
        }
        __syncthreads();
        #pragma unroll
        for (int b = 0; b < 2; ++b) {
            float s_val = (dl < lim) ? sraw[b][dl * 9 + h] : -1e30f;
            float mc = s_val;
            #pragma unroll
            for (int m = 1; m < 32; m <<= 1) mc = fmaxf(mc, __shfl_xor(mc, m, 64));
            float m_new = fmaxf(m_run[b], mc);
            float wgt = __expf(s_val - m_new);
            float sum = wgt;
            #pragma unroll
            for (int m = 1; m < 32; m <<= 1) sum += __shfl_xor(sum, m, 64);
            float alpha = __expf(m_run[b] - m_new);
            l_run[b] = l_run[b] * alpha + sum;
            m_run[b] = m_new;
            scw[b][t] = wgt;
            if (dl == 0) alpha_l[b][h] = alpha;
        }
        __syncthreads();
        #pragma unroll
        for (int b = 0; b < 2; ++b) {
            float av = alpha_l[b][hw];
            o[b][0] *= av; o[b][1] *= av; o[b][2] *= av; o[b][3] *= av;
            #pragma unroll
            for (int s = 0; s < 8; ++s) {
                int r = (s << 2) + w;
                if (r < lim) {
                    int j = nbr[base + r];
                    float wg = scw[b][(hw << 5) + r];
                    bf16x4 vv = *(const bf16x4*)(Vb16 + (((size_t)((b << 11) + j)) << 8) + (lane << 2));
                    o[b][0] = fmaf(wg, (float)vv.x, o[b][0]);
                    o[b][1] = fmaf(wg, (float)vv.y, o[b][1]);
                    o[b][2] = fmaf(wg, (float)vv.z, o[b][2]);
                    o[b][3] = fmaf(wg, (float)vv.w, o[b][3]);
                }
            }
        }
    }
    if (dl == 0) {
        linv_l[0][h] = (l_run[0] > 0.f) ? 1.f / l_run[0] : 0.f;
        linv_l[1][h] = (l_run[1] > 0.f) ? 1.f / l_run[1] : 0.f;
    }
    #pragma unroll
    for (int b = 0; b < 2; ++b) {
        __syncthreads();
        obuf[w][(lane << 2) + 0] = o[b][0];
        obuf[w][(lane << 2) + 1] = o[b][1];
        obuf[w][(lane << 2) + 2] = o[b][2];
        obuf[w][(lane << 2) + 3] = o[b][3];
        __syncthreads();
        float val = obuf[0][t] + obuf[1][t] + obuf[2][t] + obuf[3][t];
        attnb[(((size_t)((b << 11) + i)) << 8) + t] = val * linv_l[b][t >> 5];
    }
}

__global__ __launch_bounds__(256) void out_ln_kernel(
    const float* __restrict__ attnb, const float* __restrict__ Wo,
    const float* __restrict__ x, const float* __restrict__ gamma,
    const float* __restrict__ beta, float* __restrict__ out)
{
    __shared__ bf16_t As[16 * LDA2];
    __shared__ __align__(16) char wbuf[256 * LDA2 * sizeof(bf16_t)];
    bf16_t* Ws = (bf16_t*)wbuf;
    float* yb = (float*)wbuf;
    int t = threadIdx.x;
    int lane = t & 63, w = t >> 6;
    int ml = lane & 15, quad = lane >> 4;
    int m0 = blockIdx.x * 16;
    f32x4 acc[4];
    f32x4 zero = {0.f, 0.f, 0.f, 0.f};
    acc[0] = zero; acc[1] = zero; acc[2] = zero; acc[3] = zero;
    int arow = t >> 4, acol = (t & 15) * 4;
    int wrow = t >> 3, wcol = (t & 7) * 8;

    for (int k0 = 0; k0 < Hh; k0 += 64) {
        float4 av = *(const float4*)(attnb + (size_t)(m0 + arow) * Hh + k0 + acol);
        float4 wva[8], wvb[8];
        #pragma unroll
        for (int s = 0; s < 8; ++s) {
            const float* wp = Wo + (size_t)(wrow + s * 32) * Hh + k0 + wcol;
            wva[s] = *(const float4*)wp;
            wvb[s] = *(const float4*)(wp + 4);
        }
        __syncthreads();
        bf16x4 ac = {(bf16_t)av.x, (bf16_t)av.y, (bf16_t)av.z, (bf16_t)av.w};
        *(bf16x4*)&As[arow * LDA2 + acol] = ac;
        #pragma unroll
        for (int s = 0; s < 8; ++s) {
            bf16x8 wv8 = {(bf16_t)wva[s].x, (bf16_t)wva[s].y, (bf16_t)wva[s].z, (bf16_t)wva[s].w,
                          (bf16_t)wvb[s].x, (bf16_t)wvb[s].y, (bf16_t)wvb[s].z, (bf16_t)wvb[s].w};
            *(bf16x8*)&Ws[(wrow + s * 32) * LDA2 + wcol] = wv8;
        }
        __syncthreads();
        #pragma unroll
        for (int kk = 0; kk < 64; kk += 32) {
            bf16x8 af = *(const bf16x8*)&As[ml * LDA2 + kk + quad * 8];
            #pragma unroll
            for (int ct = 0; ct < 4; ++ct) {
                bf16x8 bfr = *(const bf16x8*)&Ws[(w * 64 + ct * 16 + ml) * LDA2 + kk + quad * 8];
                acc[ct] = __builtin_amdgcn_mfma_f32_16x16x32_bf16(af, bfr, acc[ct], 0, 0, 0);
            }
        }
    }
    __syncthreads();
    #pragma unroll
    for (int ct = 0; ct < 4; ++ct)
        #pragma unroll
        for (int r = 0; r < 4; ++r) {
            int row = quad * 4 + r;
            int col = w * 64 + ct * 16 + ml;
            yb[row * 260 + col] = acc[ct][r] + x[(size_t)(m0 + row) * Hh + col];
        }
    __syncthreads();
    for (int rr = 0; rr < 4; ++rr) {
        int row = w * 4 + rr;
        float4 v = *(const float4*)&yb[row * 260 + lane * 4];
        float sum = v.x + v.y + v.z + v.w;
        #pragma unroll
        for (int m = 1; m < 64; m <<= 1) sum += __shfl_xor(sum, m, 64);
        float mu = sum * (1.f / Hh);
        float4 d = {v.x - mu, v.y - mu, v.z - mu, v.w - mu};
        float ss = d.x * d.x + d.y * d.y + d.z * d.z + d.w * d.w;
        #pragma unroll
        for (int m = 1; m < 64; m <<= 1) ss += __shfl_xor(ss, m, 64);
        float r = rsqrtf(ss * (1.f / Hh) + LN_EPS);
        float4 g  = *(const float4*)(gamma + lane * 4);
        float4 bt = *(const float4*)(beta + lane * 4);
        float4 ov = {d.x * r * g.x + bt.x, d.y * r * g.y + bt.y,
                     d.z * r * g.z + bt.z, d.w * r * g.w + bt.w};
        *(float4*)(out + (size_t)(m0 + row) * Hh + lane * 4) = ov;
    }
}

extern "C" void kernel_launch(void* const* d_in, const int* in_sizes, int n_in,
                              void* d_out, int out_size, void* d_ws, size_t ws_size,
                              hipStream_t stream) {
    const float* x     = (const float*)d_in[0];
    const int*   ei    = (const int*)d_in[1];
    // d_in[2] = edge_weights: unused by the reference
    const float* Wq    = (const float*)d_in[3];
    const float* Wk    = (const float*)d_in[4];
    const float* Wv    = (const float*)d_in[5];
    const float* Wo    = (const float*)d_in[6];
    const float* gamma = (const float*)d_in[7];
    const float* beta  = (const float*)d_in[8];
    float* out = (float*)d_out;

    const int NTOK = Bb * Nn * Hh;  // 1048576
    float*  Qb    = (float*)d_ws;
    bf16_t* Kb16  = (bf16_t*)(Qb + NTOK);
    bf16_t* Vb16  = Kb16 + NTOK;
    float*  attnb = (float*)(Vb16 + NTOK);
    unsigned int* mask = (unsigned int*)(attnb + NTOK);

    static int coop_blocks = -2;   // -2 = not probed yet; 0 = fallback
    if (coop_blocks == -2) {
        int per_cu = 0;
        hipError_t e = hipOccupancyMaxActiveBlocksPerMultiprocessor(&per_cu, fused_kernel, 256, 0);
        if (e != hipSuccess || per_cu <= 0) {
            coop_blocks = 0;
        } else {
            int num_cu = 256;
            hipDeviceProp_t prop;
            int dev = 0;
            if (hipGetDevice(&dev) == hipSuccess && hipGetDeviceProperties(&prop, dev) == hipSuccess)
                num_cu = prop.multiProcessorCount;
            long cap = (long)per_cu * num_cu;
            coop_blocks = (int)(cap < 1024 ? cap : 1024);
        }
    }

    if (coop_blocks > 0) {
        void* args[] = {
            (void*)&x, (void*)&ei, (void*)&Wq, (void*)&Wk, (void*)&Wv,
            (void*)&Wo, (void*)&gamma, (void*)&beta,
            (void*)&Qb, (void*)&Kb16, (void*)&Vb16,
            (void*)&attnb, (void*)&mask, (void*)&out};
        hipError_t e = hipLaunchCooperativeKernel((const void*)fused_kernel,
                                                  dim3(coop_blocks), dim3(256),
                                                  args, 0, stream);
        if (e == hipSuccess) return;
        coop_blocks = 0;   // permanent fallback
    }

    hipMemsetAsync(mask, 0, Nn * MW * sizeof(unsigned int), stream);
    hipLaunchKernelGGL(build_mask_kernel, dim3(NEDGE / 256), dim3(256), 0, stream, ei, mask);
    hipLaunchKernelGGL(qkv_gemm3_kernel, dim3((Bb * Nn) / 64, 12), dim3(256), 0, stream,
                       x, Wq, Wk, Wv, Qb, Kb16, Vb16);
    hipLaunchKernelGGL(attn6_kernel, dim3(Bb * Nn), dim3(256), 0, stream,
                       Qb, Kb16, Vb16, mask, attnb);
    hipLaunchKernelGGL(out_ln_kernel, dim3((Bb * Nn) / 16), dim3(256), 0, stream,
                       attnb, Wo, x, gamma, beta, out);
}

// Round 3
// 144.729 us; speedup vs baseline: 2.9986x; 2.9986x over previous
//
#include <hip/hip_runtime.h>
#include <math.h>

#define Bb 2
#define Nn 2048
#define Hh 256
#define NH 8
#define HD 32
#define NEDGE 65536
#define LN_EPS 1e-5f
#define MW 64          // mask words per row = N/32
#define LDA2 72

typedef __bf16 bf16_t;
typedef bf16_t bf16x8 __attribute__((ext_vector_type(8)));
typedef bf16_t bf16x4 __attribute__((ext_vector_type(4)));
typedef float f32x4 __attribute__((ext_vector_type(4)));

// ===========================================================================
// K0: QKV GEMM (units 0..767) + mask zero (768..799) + Wo->bf16 cvt (800..863)
// All three works are mutually independent; one launch, one ramp.
// ===========================================================================
__global__ __launch_bounds__(256) void prep_kernel(
    const float* __restrict__ x,
    const float* __restrict__ Wq, const float* __restrict__ Wk, const float* __restrict__ Wv,
    const float* __restrict__ Wo,
    float* __restrict__ Qb, bf16_t* __restrict__ Kb16, bf16_t* __restrict__ Vb16,
    bf16_t* __restrict__ Wob, unsigned int* __restrict__ mask)
{
    __shared__ bf16_t As[64 * LDA2];
    __shared__ bf16_t Ws[64 * LDA2];
    const int u = blockIdx.x;
    const int t = threadIdx.x;

    if (u >= 768) {
        if (u < 800) {
            // ---- zero adjacency bitmask: 32 blocks x 256 thr x 4 uint4 ----
            uint4* m4 = (uint4*)mask;
            const uint4 z = make_uint4(0, 0, 0, 0);
            int b0 = (u - 768) * 1024 + t;
            #pragma unroll
            for (int r = 0; r < 4; ++r) m4[b0 + r * 256] = z;
        } else {
            // ---- Wo fp32 -> bf16 row-major: 64 blocks x 256 thr x float4 ----
            int i = (u - 800) * 256 + t;
            float4 v = ((const float4*)Wo)[i];
            bf16x4 o = {(bf16_t)v.x, (bf16_t)v.y, (bf16_t)v.z, (bf16_t)v.w};
            ((bf16x4*)Wob)[i] = o;
        }
        return;
    }

    // ---- one 64x64 QKV GEMM tile (bf16 MFMA, 4 waves 2x2) ----
    const int lane = t & 63, w = t >> 6;
    const int wm = w & 1, wn = w >> 1;
    const int ml = lane & 15, quad = lane >> 4;
    const int m0 = (u & 63) << 6;
    const int ysel = u >> 6;
    const int wsel = ysel >> 2;
    const float* W = (wsel == 0) ? Wq : ((wsel == 1) ? Wk : Wv);
    const int n0 = (ysel & 3) << 6;
    const int srow = t >> 3, scol = (t & 7) * 8;
    f32x4 acc[2][2];
    f32x4 zero = {0.f, 0.f, 0.f, 0.f};
    acc[0][0] = zero; acc[0][1] = zero; acc[1][0] = zero; acc[1][1] = zero;

    for (int k0 = 0; k0 < Hh; k0 += 64) {
        float4 a[2][2], bwt[2][2];
        #pragma unroll
        for (int s = 0; s < 2; ++s) {
            const float* ap = x + (size_t)(m0 + srow + s * 32) * Hh + k0 + scol;
            a[s][0] = *(const float4*)ap;
            a[s][1] = *(const float4*)(ap + 4);
            const float* bp = W + (size_t)(n0 + srow + s * 32) * Hh + k0 + scol;
            bwt[s][0] = *(const float4*)bp;
            bwt[s][1] = *(const float4*)(bp + 4);
        }
        __syncthreads();
        #pragma unroll
        for (int s = 0; s < 2; ++s) {
            bf16x8 av = {(bf16_t)a[s][0].x, (bf16_t)a[s][0].y, (bf16_t)a[s][0].z, (bf16_t)a[s][0].w,
                         (bf16_t)a[s][1].x, (bf16_t)a[s][1].y, (bf16_t)a[s][1].z, (bf16_t)a[s][1].w};
            bf16x8 bv = {(bf16_t)bwt[s][0].x, (bf16_t)bwt[s][0].y, (bf16_t)bwt[s][0].z, (bf16_t)bwt[s][0].w,
                         (bf16_t)bwt[s][1].x, (bf16_t)bwt[s][1].y, (bf16_t)bwt[s][1].z, (bf16_t)bwt[s][1].w};
            *(bf16x8*)&As[(srow + s * 32) * LDA2 + scol] = av;
            *(bf16x8*)&Ws[(srow + s * 32) * LDA2 + scol] = bv;
        }
        __syncthreads();
        #pragma unroll
        for (int kk = 0; kk < 64; kk += 32) {
            bf16x8 af[2], bfr[2];
            #pragma unroll
            for (int i = 0; i < 2; ++i) {
                af[i]  = *(const bf16x8*)&As[(wm * 32 + i * 16 + ml) * LDA2 + kk + quad * 8];
                bfr[i] = *(const bf16x8*)&Ws[(wn * 32 + i * 16 + ml) * LDA2 + kk + quad * 8];
            }
            #pragma unroll
            for (int i = 0; i < 2; ++i)
                #pragma unroll
                for (int j = 0; j < 2; ++j)
                    acc[i][j] = __builtin_amdgcn_mfma_f32_16x16x32_bf16(af[i], bfr[j], acc[i][j], 0, 0, 0);
        }
    }
    bf16_t* Ob16 = (wsel == 1) ? Kb16 : Vb16;
    #pragma unroll
    for (int i = 0; i < 2; ++i)
        #pragma unroll
        for (int j = 0; j < 2; ++j)
            #pragma unroll
            for (int r = 0; r < 4; ++r) {
                int mg = m0 + wm * 32 + i * 16 + quad * 4 + r;
                int ng = n0 + wn * 32 + j * 16 + ml;
                float v = acc[i][j][r];
                if (wsel == 0) Qb[(size_t)mg * Hh + ng] = v;
                else           Ob16[(size_t)mg * Hh + ng] = (bf16_t)v;
            }
}

// ===========================================================================
// K1: build adjacency bitmask from edge list (needs K0's zeroed mask).
// ===========================================================================
__global__ void build_mask_kernel(const int* __restrict__ ei, unsigned int* __restrict__ mask) {
    int e = blockIdx.x * blockDim.x + threadIdx.x;
    if (e >= NEDGE) return;
    int src = ei[e];
    int dst = ei[NEDGE + e];
    atomicOr(&mask[src * MW + (dst >> 5)], 1u << (dst & 31));
}

// ===========================================================================
// K2: fused sparse attention + out-projection + residual + LayerNorm.
// Block per graph row i, both batches. Attention identical to attn6.
// Epilogue: attn rows (M=2) -> bf16 in LDS, out = attn @ Wo^T via MFMA with
// B-fragments read directly from L2-hot bf16 Wo (C rows 2..15 ignored;
// A lanes ml>=2 fed zeros), then residual + LN, write final out.
// Same k-summation order as the old out_ln kernel -> bit-identical result.
// ===========================================================================
__global__ __launch_bounds__(256) void attn_fused_kernel(
    const float* __restrict__ Qb, const bf16_t* __restrict__ Kb16, const bf16_t* __restrict__ Vb16,
    const unsigned int* __restrict__ mask, const bf16_t* __restrict__ Wob,
    const float* __restrict__ x, const float* __restrict__ gamma, const float* __restrict__ beta,
    float* __restrict__ out)
{
    __shared__ unsigned short nbr[Nn];   // 4 KB
    __shared__ float qs[2][Hh];          // 2 KB
    __shared__ float sraw[2][288];       // 2.25 KB
    __shared__ float scw[2][Hh];         // 2 KB
    __shared__ float alpha_l[2][NH];
    __shared__ float linv_l[2][NH];
    __shared__ float obuf[4][Hh];        // 4 KB
    __shared__ bf16_t aLDS[2 * Hh];      // 1 KB  (bf16 attn rows, M=2)
    __shared__ float ybuf[2][Hh];        // 2 KB  (y = attn@Wo^T + x)
    __shared__ int nn_sh;
    const int i = blockIdx.x;
    const int t = threadIdx.x;
    const int h = t >> 5, dl = t & 31;
    const int w = t >> 6, lane = t & 63;
    const int ml = lane & 15, quad = lane >> 4;
    const int hw = lane >> 3;            // head owning cols 4*lane..4*lane+3

    // ---- neighbor-list decode (wave 0) + Q rows load ----
    if (t < 64) {
        unsigned int bits = mask[i * MW + t];
        int cnt = __popc(bits);
        int incl = cnt;
        #pragma unroll
        for (int off = 1; off < 64; off <<= 1) {
            int v = __shfl_up(incl, off, 64);
            if (t >= off) incl += v;
        }
        int idx = incl - cnt;
        unsigned int bb = bits;
        while (bb) {
            int bit = __ffs(bb) - 1;
            nbr[idx++] = (unsigned short)(t * 32 + bit);
            bb &= bb - 1;
        }
        if (t == 63) nn_sh = incl;
    }
    qs[0][t] = Qb[(size_t)i * Hh + t];
    qs[1][t] = Qb[(size_t)(Nn + i) * Hh + t];
    __syncthreads();
    int nn = nn_sh;

    // ---- online-softmax sparse attention over neighbor chunks ----
    float m_run[2] = {-1e30f, -1e30f};
    float l_run[2] = {0.f, 0.f};
    float o[2][4] = {{0.f, 0.f, 0.f, 0.f}, {0.f, 0.f, 0.f, 0.f}};
    const float scale = 0.17677669529663687f;  // 1/sqrt(32)
    int nch = (nn + 31) >> 5;
    for (int c = 0; c < nch; ++c) {
        int base = c << 5;
        int lim = min(32, nn - base);
        #pragma unroll
        for (int b = 0; b < 2; ++b) {
            float4 qv = *(const float4*)&qs[b][lane << 2];
            #pragma unroll
            for (int s = 0; s < 8; ++s) {
                int r = (s << 2) + w;
                if (r < lim) {
                    int j = nbr[base + r];
                    bf16x4 kv = *(const bf16x4*)(Kb16 + (((size_t)((b << 11) + j)) << 8) + (lane << 2));
                    float p = fmaf((float)kv.x, qv.x, fmaf((float)kv.y, qv.y,
                              fmaf((float)kv.z, qv.z, (float)kv.w * qv.w)));
                    p += __shfl_xor(p, 1, 64);
                    p += __shfl_xor(p, 2, 64);
                    p += __shfl_xor(p, 4, 64);
                    if ((lane & 7) == 0) sraw[b][r * 9 + (lane >> 3)] = p * scale;
                }
            }
        }
        __syncthreads();
        #pragma unroll
        for (int b = 0; b < 2; ++b) {
            float s_val = (dl < lim) ? sraw[b][dl * 9 + h] : -1e30f;
            float mc = s_val;
            #pragma unroll
            for (int m = 1; m < 32; m <<= 1) mc = fmaxf(mc, __shfl_xor(mc, m, 64));
            float m_new = fmaxf(m_run[b], mc);
            float wgt = __expf(s_val - m_new);
            float sum = wgt;
            #pragma unroll
            for (int m = 1; m < 32; m <<= 1) sum += __shfl_xor(sum, m, 64);
            float alpha = __expf(m_run[b] - m_new);
            l_run[b] = l_run[b] * alpha + sum;
            m_run[b] = m_new;
            scw[b][t] = wgt;
            if (dl == 0) alpha_l[b][h] = alpha;
        }
        __syncthreads();
        #pragma unroll
        for (int b = 0; b < 2; ++b) {
            float av = alpha_l[b][hw];
            o[b][0] *= av; o[b][1] *= av; o[b][2] *= av; o[b][3] *= av;
            #pragma unroll
            for (int s = 0; s < 8; ++s) {
                int r = (s << 2) + w;
                if (r < lim) {
                    int j = nbr[base + r];
                    float wg = scw[b][(hw << 5) + r];
                    bf16x4 vv = *(const bf16x4*)(Vb16 + (((size_t)((b << 11) + j)) << 8) + (lane << 2));
                    o[b][0] = fmaf(wg, (float)vv.x, o[b][0]);
                    o[b][1] = fmaf(wg, (float)vv.y, o[b][1]);
                    o[b][2] = fmaf(wg, (float)vv.z, o[b][2]);
                    o[b][3] = fmaf(wg, (float)vv.w, o[b][3]);
                }
            }
        }
    }
    if (dl == 0) {
        linv_l[0][h] = (l_run[0] > 0.f) ? 1.f / l_run[0] : 0.f;
        linv_l[1][h] = (l_run[1] > 0.f) ? 1.f / l_run[1] : 0.f;
    }
    // ---- merge wave partials; attn rows -> bf16 LDS ----
    #pragma unroll
    for (int b = 0; b < 2; ++b) {
        __syncthreads();   // b=0: linv visible; b=1: prev obuf reads done
        obuf[w][(lane << 2) + 0] = o[b][0];
        obuf[w][(lane << 2) + 1] = o[b][1];
        obuf[w][(lane << 2) + 2] = o[b][2];
        obuf[w][(lane << 2) + 3] = o[b][3];
        __syncthreads();
        float val = (obuf[0][t] + obuf[1][t] + obuf[2][t] + obuf[3][t]) * linv_l[b][t >> 5];
        aLDS[(b << 8) + t] = (bf16_t)val;
    }
    __syncthreads();

    // ---- out-projection: C[b][n] = sum_k attn[b][k] * Wo[n][k] via MFMA ----
    // wave w owns n-tiles w*4..w*4+3 (cols w*64..w*64+63).
    f32x4 pacc[4];
    {
        f32x4 pz = {0.f, 0.f, 0.f, 0.f};
        pacc[0] = pz; pacc[1] = pz; pacc[2] = pz; pacc[3] = pz;
    }
    const bf16x8 zero8 = {(bf16_t)0.f, (bf16_t)0.f, (bf16_t)0.f, (bf16_t)0.f,
                          (bf16_t)0.f, (bf16_t)0.f, (bf16_t)0.f, (bf16_t)0.f};
    #pragma unroll
    for (int k8 = 0; k8 < 8; ++k8) {           // 8 x 32-wide k-steps, ascending
        bf16x8 af = zero8;
        if (ml < 2) af = *(const bf16x8*)&aLDS[(ml << 8) + k8 * 32 + quad * 8];
        #pragma unroll
        for (int ct = 0; ct < 4; ++ct) {
            const bf16_t* bp = Wob + (size_t)(w * 64 + ct * 16 + ml) * Hh + k8 * 32 + quad * 8;
            bf16x8 bfr = *(const bf16x8*)bp;
            pacc[ct] = __builtin_amdgcn_mfma_f32_16x16x32_bf16(af, bfr, pacc[ct], 0, 0, 0);
        }
    }
    // C rows: row = quad*4 + r -> rows 0,1 live in quad==0, r=0,1.
    if (quad == 0) {
        #pragma unroll
        for (int ct = 0; ct < 4; ++ct) {
            int col = w * 64 + ct * 16 + ml;
            #pragma unroll
            for (int r = 0; r < 2; ++r)
                ybuf[r][col] = pacc[ct][r] + x[(size_t)((r << 11) + i) * Hh + col];
        }
    }
    __syncthreads();

    // ---- LayerNorm: wave w<2 handles batch b=w ----
    if (w < 2) {
        float4 v = *(const float4*)&ybuf[w][lane << 2];
        float sum = v.x + v.y + v.z + v.w;
        #pragma unroll
        for (int m = 1; m < 64; m <<= 1) sum += __shfl_xor(sum, m, 64);
        float mu = sum * (1.f / Hh);
        float4 d = {v.x - mu, v.y - mu, v.z - mu, v.w - mu};
        float ss = d.x * d.x + d.y * d.y + d.z * d.z + d.w * d.w;
        #pragma unroll
        for (int m = 1; m < 64; m <<= 1) ss += __shfl_xor(ss, m, 64);
        float r = rsqrtf(ss * (1.f / Hh) + LN_EPS);
        float4 g  = *(const float4*)(gamma + (lane << 2));
        float4 bt = *(const float4*)(beta + (lane << 2));
        float4 ov = {d.x * r * g.x + bt.x, d.y * r * g.y + bt.y,
                     d.z * r * g.z + bt.z, d.w * r * g.w + bt.w};
        *(float4*)(out + (size_t)((w << 11) + i) * Hh + (lane << 2)) = ov;
    }
}

extern "C" void kernel_launch(void* const* d_in, const int* in_sizes, int n_in,
                              void* d_out, int out_size, void* d_ws, size_t ws_size,
                              hipStream_t stream) {
    const float* x     = (const float*)d_in[0];
    const int*   ei    = (const int*)d_in[1];
    // d_in[2] = edge_weights: unused by the reference
    const float* Wq    = (const float*)d_in[3];
    const float* Wk    = (const float*)d_in[4];
    const float* Wv    = (const float*)d_in[5];
    const float* Wo    = (const float*)d_in[6];
    const float* gamma = (const float*)d_in[7];
    const float* beta  = (const float*)d_in[8];
    float* out = (float*)d_out;

    const int NTOK = Bb * Nn * Hh;  // 1048576
    float*  Qb    = (float*)d_ws;
    bf16_t* Kb16  = (bf16_t*)(Qb + NTOK);
    bf16_t* Vb16  = Kb16 + NTOK;
    unsigned int* mask = (unsigned int*)(Vb16 + NTOK);
    bf16_t* Wob   = (bf16_t*)(mask + Nn * MW);

    hipLaunchKernelGGL(prep_kernel, dim3(864), dim3(256), 0, stream,
                       x, Wq, Wk, Wv, Wo, Qb, Kb16, Vb16, Wob, mask);
    hipLaunchKernelGGL(build_mask_kernel, dim3(NEDGE / 256), dim3(256), 0, stream, ei, mask);
    hipLaunchKernelGGL(attn_fused_kernel, dim3(Nn), dim3(256), 0, stream,
                       Qb, Kb16, Vb16, mask, Wob, x, gamma, beta, out);
}

// Round 4
// 116.143 us; speedup vs baseline: 3.7366x; 1.2461x over previous
//
#include <hip/hip_runtime.h>
#include <math.h>

#define Bb 2
#define Nn 2048
#define Hh 256
#define NH 8
#define HD 32
#define NEDGE 65536
#define LN_EPS 1e-5f
#define MW 64          // mask words per row = N/32
#define LDA2 72

typedef __bf16 bf16_t;
typedef bf16_t bf16x8 __attribute__((ext_vector_type(8)));
typedef bf16_t bf16x4 __attribute__((ext_vector_type(4)));
typedef float f32x4 __attribute__((ext_vector_type(4)));

// ===========================================================================
// K0: QKV GEMM (units 0..767) + mask zero (units 768..799).
// ===========================================================================
__global__ __launch_bounds__(256) void prep_kernel(
    const float* __restrict__ x,
    const float* __restrict__ Wq, const float* __restrict__ Wk, const float* __restrict__ Wv,
    float* __restrict__ Qb, bf16_t* __restrict__ Kb16, bf16_t* __restrict__ Vb16,
    unsigned int* __restrict__ mask)
{
    __shared__ bf16_t As[64 * LDA2];
    __shared__ bf16_t Ws[64 * LDA2];
    const int u = blockIdx.x;
    const int t = threadIdx.x;

    if (u >= 768) {
        // ---- zero adjacency bitmask: 32 blocks x 256 thr x 4 uint4 ----
        uint4* m4 = (uint4*)mask;
        const uint4 z = make_uint4(0, 0, 0, 0);
        int b0 = (u - 768) * 1024 + t;
        #pragma unroll
        for (int r = 0; r < 4; ++r) m4[b0 + r * 256] = z;
        return;
    }

    // ---- one 64x64 QKV GEMM tile (bf16 MFMA, 4 waves 2x2) ----
    const int lane = t & 63, w = t >> 6;
    const int wm = w & 1, wn = w >> 1;
    const int ml = lane & 15, quad = lane >> 4;
    const int m0 = (u & 63) << 6;
    const int ysel = u >> 6;
    const int wsel = ysel >> 2;
    const float* W = (wsel == 0) ? Wq : ((wsel == 1) ? Wk : Wv);
    const int n0 = (ysel & 3) << 6;
    const int srow = t >> 3, scol = (t & 7) * 8;
    f32x4 acc[2][2];
    f32x4 zero = {0.f, 0.f, 0.f, 0.f};
    acc[0][0] = zero; acc[0][1] = zero; acc[1][0] = zero; acc[1][1] = zero;

    for (int k0 = 0; k0 < Hh; k0 += 64) {
        float4 a[2][2], bwt[2][2];
        #pragma unroll
        for (int s = 0; s < 2; ++s) {
            const float* ap = x + (size_t)(m0 + srow + s * 32) * Hh + k0 + scol;
            a[s][0] = *(const float4*)ap;
            a[s][1] = *(const float4*)(ap + 4);
            const float* bp = W + (size_t)(n0 + srow + s * 32) * Hh + k0 + scol;
            bwt[s][0] = *(const float4*)bp;
            bwt[s][1] = *(const float4*)(bp + 4);
        }
        __syncthreads();
        #pragma unroll
        for (int s = 0; s < 2; ++s) {
            bf16x8 av = {(bf16_t)a[s][0].x, (bf16_t)a[s][0].y, (bf16_t)a[s][0].z, (bf16_t)a[s][0].w,
                         (bf16_t)a[s][1].x, (bf16_t)a[s][1].y, (bf16_t)a[s][1].z, (bf16_t)a[s][1].w};
            bf16x8 bv = {(bf16_t)bwt[s][0].x, (bf16_t)bwt[s][0].y, (bf16_t)bwt[s][0].z, (bf16_t)bwt[s][0].w,
                         (bf16_t)bwt[s][1].x, (bf16_t)bwt[s][1].y, (bf16_t)bwt[s][1].z, (bf16_t)bwt[s][1].w};
            *(bf16x8*)&As[(srow + s * 32) * LDA2 + scol] = av;
            *(bf16x8*)&Ws[(srow + s * 32) * LDA2 + scol] = bv;
        }
        __syncthreads();
        #pragma unroll
        for (int kk = 0; kk < 64; kk += 32) {
            bf16x8 af[2], bfr[2];
            #pragma unroll
            for (int i = 0; i < 2; ++i) {
                af[i]  = *(const bf16x8*)&As[(wm * 32 + i * 16 + ml) * LDA2 + kk + quad * 8];
                bfr[i] = *(const bf16x8*)&Ws[(wn * 32 + i * 16 + ml) * LDA2 + kk + quad * 8];
            }
            #pragma unroll
            for (int i = 0; i < 2; ++i)
                #pragma unroll
                for (int j = 0; j < 2; ++j)
                    acc[i][j] = __builtin_amdgcn_mfma_f32_16x16x32_bf16(af[i], bfr[j], acc[i][j], 0, 0, 0);
        }
    }
    bf16_t* Ob16 = (wsel == 1) ? Kb16 : Vb16;
    #pragma unroll
    for (int i = 0; i < 2; ++i)
        #pragma unroll
        for (int j = 0; j < 2; ++j)
            #pragma unroll
            for (int r = 0; r < 4; ++r) {
                int mg = m0 + wm * 32 + i * 16 + quad * 4 + r;
                int ng = n0 + wn * 32 + j * 16 + ml;
                float v = acc[i][j][r];
                if (wsel == 0) Qb[(size_t)mg * Hh + ng] = v;
                else           Ob16[(size_t)mg * Hh + ng] = (bf16_t)v;
            }
}

// ===========================================================================
// K1: build adjacency bitmask from edge list (needs K0's zeroed mask).
// ===========================================================================
__global__ void build_mask_kernel(const int* __restrict__ ei, unsigned int* __restrict__ mask) {
    int e = blockIdx.x * blockDim.x + threadIdx.x;
    if (e >= NEDGE) return;
    int src = ei[e];
    int dst = ei[NEDGE + e];
    atomicOr(&mask[src * MW + (dst >> 5)], 1u << (dst & 31));
}

// ===========================================================================
// K2: sparse attention v7 — WAVE per (batch,row), fully in-register online
// softmax. No __syncthreads in the neighbor loop (one barrier after decode).
// Lane l owns dims 4l..4l+3 (head = l>>3). Per neighbor: K/V bf16x4 load,
// 4-FMA dot, 3x shfl_xor 8-lane head reduce, per-lane online m/l/o update.
// Next neighbor's K/V prefetched (sentinel nbr[nn]=0 keeps address valid).
// 1024 blocks x 4 waves = 4096 row-waves, all co-resident (16.5 KB LDS).
// ===========================================================================
__global__ __launch_bounds__(256) void attn7_kernel(
    const float* __restrict__ Qb, const bf16_t* __restrict__ Kb16, const bf16_t* __restrict__ Vb16,
    const unsigned int* __restrict__ mask, float* __restrict__ attnb)
{
    __shared__ unsigned short nbr[4][2048];   // 16 KB, worst-case full row
    const int t = threadIdx.x;
    const int w = t >> 6, lane = t & 63;
    const int i = (blockIdx.x << 1) + (w >> 1);   // graph row
    const int b = w & 1;                          // batch

    // ---- decode mask row i into this wave's neighbor list ----
    unsigned int bits = mask[i * MW + lane];
    int cnt = __popc(bits);
    int incl = cnt;
    #pragma unroll
    for (int off = 1; off < 64; off <<= 1) {
        int v = __shfl_up(incl, off, 64);
        if (lane >= off) incl += v;
    }
    int idx = incl - cnt;
    unsigned int bb = bits;
    while (bb) {
        int bit = __ffs(bb) - 1;
        nbr[w][idx++] = (unsigned short)(lane * 32 + bit);
        bb &= bb - 1;
    }
    int nn = __shfl(incl, 63, 64);
    if (lane == 63) nbr[w][idx] = 0;   // sentinel: keeps prefetch addr valid
    __syncthreads();                   // decode LDS writes visible wave-wide

    const int off4 = lane << 2;
    const float4 qv = *(const float4*)(Qb + (size_t)((b << 11) + i) * Hh + off4);
    const bf16_t* kb = Kb16 + (((size_t)(b << 11)) << 8);
    const bf16_t* vb = Vb16 + (((size_t)(b << 11)) << 8);
    const float scale = 0.17677669529663687f;  // 1/sqrt(32)

    float m_run = -1e30f, l_run = 0.f;
    float o0 = 0.f, o1 = 0.f, o2 = 0.f, o3 = 0.f;
    if (nn > 0) {
        int j = nbr[w][0];
        bf16x4 kv = *(const bf16x4*)(kb + ((size_t)j << 8) + off4);
        bf16x4 vv = *(const bf16x4*)(vb + ((size_t)j << 8) + off4);
        for (int n = 0; n < nn; ++n) {
            int jn = nbr[w][n + 1];    // sentinel makes this always valid
            bf16x4 kn = *(const bf16x4*)(kb + ((size_t)jn << 8) + off4);
            bf16x4 vn = *(const bf16x4*)(vb + ((size_t)jn << 8) + off4);
            float p = fmaf((float)kv.x, qv.x, fmaf((float)kv.y, qv.y,
                      fmaf((float)kv.z, qv.z, (float)kv.w * qv.w)));
            p += __shfl_xor(p, 1, 64);
            p += __shfl_xor(p, 2, 64);
            p += __shfl_xor(p, 4, 64);   // every lane in 8-lane head group has head dot
            p *= scale;
            float m_new = fmaxf(m_run, p);
            float alpha = __expf(m_run - m_new);
            float wgt   = __expf(p - m_new);
            l_run = fmaf(l_run, alpha, wgt);
            o0 = fmaf(o0, alpha, wgt * (float)vv.x);
            o1 = fmaf(o1, alpha, wgt * (float)vv.y);
            o2 = fmaf(o2, alpha, wgt * (float)vv.z);
            o3 = fmaf(o3, alpha, wgt * (float)vv.w);
            m_run = m_new;
            kv = kn; vv = vn;
        }
    }
    float linv = (l_run > 0.f) ? 1.f / l_run : 0.f;
    float4 ov = {o0 * linv, o1 * linv, o2 * linv, o3 * linv};
    *(float4*)(attnb + ((size_t)((b << 11) + i) << 8) + off4) = ov;
}

// ===========================================================================
// K3: out = LayerNorm(attn @ Wo^T + x): 16 full rows per block, fp32 Wo read
// directly and converted to bf16 in the staging path (round-1 proven).
// ===========================================================================
__global__ __launch_bounds__(256) void out_ln_kernel(
    const float* __restrict__ attnb, const float* __restrict__ Wo,
    const float* __restrict__ x, const float* __restrict__ gamma,
    const float* __restrict__ beta, float* __restrict__ out)
{
    __shared__ bf16_t As[16 * LDA2];
    __shared__ __align__(16) char wbuf[256 * LDA2 * sizeof(bf16_t)];  // 36.9 KB
    bf16_t* Ws = (bf16_t*)wbuf;
    float* yb = (float*)wbuf;          // 16 x 260 fp32, aliased after use
    int t = threadIdx.x;
    int lane = t & 63, w = t >> 6;
    int ml = lane & 15, quad = lane >> 4;
    int m0 = blockIdx.x * 16;
    f32x4 acc[4];
    f32x4 zero = {0.f, 0.f, 0.f, 0.f};
    acc[0] = zero; acc[1] = zero; acc[2] = zero; acc[3] = zero;
    int arow = t >> 4, acol = (t & 15) * 4;
    int wrow = t >> 3, wcol = (t & 7) * 8;

    for (int k0 = 0; k0 < Hh; k0 += 64) {
        float4 av = *(const float4*)(attnb + (size_t)(m0 + arow) * Hh + k0 + acol);
        float4 wva[8], wvb[8];
        #pragma unroll
        for (int s = 0; s < 8; ++s) {
            const float* wp = Wo + (size_t)(wrow + s * 32) * Hh + k0 + wcol;
            wva[s] = *(const float4*)wp;
            wvb[s] = *(const float4*)(wp + 4);
        }
        __syncthreads();
        bf16x4 ac = {(bf16_t)av.x, (bf16_t)av.y, (bf16_t)av.z, (bf16_t)av.w};
        *(bf16x4*)&As[arow * LDA2 + acol] = ac;
        #pragma unroll
        for (int s = 0; s < 8; ++s) {
            bf16x8 wv8 = {(bf16_t)wva[s].x, (bf16_t)wva[s].y, (bf16_t)wva[s].z, (bf16_t)wva[s].w,
                          (bf16_t)wvb[s].x, (bf16_t)wvb[s].y, (bf16_t)wvb[s].z, (bf16_t)wvb[s].w};
            *(bf16x8*)&Ws[(wrow + s * 32) * LDA2 + wcol] = wv8;
        }
        __syncthreads();
        #pragma unroll
        for (int kk = 0; kk < 64; kk += 32) {
            bf16x8 af = *(const bf16x8*)&As[ml * LDA2 + kk + quad * 8];
            #pragma unroll
            for (int ct = 0; ct < 4; ++ct) {
                bf16x8 bfr = *(const bf16x8*)&Ws[(w * 64 + ct * 16 + ml) * LDA2 + kk + quad * 8];
                acc[ct] = __builtin_amdgcn_mfma_f32_16x16x32_bf16(af, bfr, acc[ct], 0, 0, 0);
            }
        }
    }
    __syncthreads();   // all Ws reads done before aliasing as yb
    #pragma unroll
    for (int ct = 0; ct < 4; ++ct)
        #pragma unroll
        for (int r = 0; r < 4; ++r) {
            int row = quad * 4 + r;
            int col = w * 64 + ct * 16 + ml;
            yb[row * 260 + col] = acc[ct][r] + x[(size_t)(m0 + row) * Hh + col];
        }
    __syncthreads();
    for (int rr = 0; rr < 4; ++rr) {
        int row = w * 4 + rr;
        float4 v = *(const float4*)&yb[row * 260 + lane * 4];
        float sum = v.x + v.y + v.z + v.w;
        #pragma unroll
        for (int m = 1; m < 64; m <<= 1) sum += __shfl_xor(sum, m, 64);
        float mu = sum * (1.f / Hh);
        float4 d = {v.x - mu, v.y - mu, v.z - mu, v.w - mu};
        float ss = d.x * d.x + d.y * d.y + d.z * d.z + d.w * d.w;
        #pragma unroll
        for (int m = 1; m < 64; m <<= 1) ss += __shfl_xor(ss, m, 64);
        float r = rsqrtf(ss * (1.f / Hh) + LN_EPS);
        float4 g  = *(const float4*)(gamma + lane * 4);
        float4 bt = *(const float4*)(beta + lane * 4);
        float4 ov = {d.x * r * g.x + bt.x, d.y * r * g.y + bt.y,
                     d.z * r * g.z + bt.z, d.w * r * g.w + bt.w};
        *(float4*)(out + (size_t)(m0 + row) * Hh + lane * 4) = ov;
    }
}

extern "C" void kernel_launch(void* const* d_in, const int* in_sizes, int n_in,
                              void* d_out, int out_size, void* d_ws, size_t ws_size,
                              hipStream_t stream) {
    const float* x     = (const float*)d_in[0];
    const int*   ei    = (const int*)d_in[1];
    // d_in[2] = edge_weights: unused by the reference
    const float* Wq    = (const float*)d_in[3];
    const float* Wk    = (const float*)d_in[4];
    const float* Wv    = (const float*)d_in[5];
    const float* Wo    = (const float*)d_in[6];
    const float* gamma = (const float*)d_in[7];
    const float* beta  = (const float*)d_in[8];
    float* out = (float*)d_out;

    const int NTOK = Bb * Nn * Hh;  // 1048576
    float*  Qb    = (float*)d_ws;
    bf16_t* Kb16  = (bf16_t*)(Qb + NTOK);
    bf16_t* Vb16  = Kb16 + NTOK;
    float*  attnb = (float*)(Vb16 + NTOK);
    unsigned int* mask = (unsigned int*)(attnb + NTOK);

    hipLaunchKernelGGL(prep_kernel, dim3(800), dim3(256), 0, stream,
                       x, Wq, Wk, Wv, Qb, Kb16, Vb16, mask);
    hipLaunchKernelGGL(build_mask_kernel, dim3(NEDGE / 256), dim3(256), 0, stream, ei, mask);
    hipLaunchKernelGGL(attn7_kernel, dim3(Nn / 2), dim3(256), 0, stream,
                       Qb, Kb16, Vb16, mask, attnb);
    hipLaunchKernelGGL(out_ln_kernel, dim3((Bb * Nn) / 16), dim3(256), 0, stream,
                       attnb, Wo, x, gamma, beta, out);
}

// Round 6
// 109.980 us; speedup vs baseline: 3.9460x; 1.0560x over previous
//
#include <hip/hip_runtime.h>
#include <math.h>

#define Bb 2
#define Nn 2048
#define Hh 256
#define NH 8
#define HD 32
#define NEDGE 65536
#define LN_EPS 1e-5f
#define MW 64          // mask words per row = N/32
#define LDA2 72
#define ALD 264        // As row stride (bf16): 528 B -> 2-way-max bank aliasing
#define NBW 2112       // nbr row stride (worst-case 2048 + sentinel, padded)

typedef __bf16 bf16_t;
typedef bf16_t bf16x8 __attribute__((ext_vector_type(8)));
typedef bf16_t bf16x4 __attribute__((ext_vector_type(4)));
typedef float f32x4 __attribute__((ext_vector_type(4)));

// ===========================================================================
// K0: QKV GEMM (units 0..767) + build mask from edges (units 768..1023).
// Mask is zeroed by a hipMemsetAsync dispatch BEFORE this kernel (stream
// order guarantees completion), so edge atomics can run concurrently with
// the GEMM tiles here.
// ===========================================================================
__global__ __launch_bounds__(256) void prep_kernel(
    const float* __restrict__ x,
    const float* __restrict__ Wq, const float* __restrict__ Wk, const float* __restrict__ Wv,
    const int* __restrict__ ei,
    float* __restrict__ Qb, bf16_t* __restrict__ Kb16, bf16_t* __restrict__ Vb16,
    unsigned int* __restrict__ mask)
{
    __shared__ bf16_t As[64 * LDA2];
    __shared__ bf16_t Ws[64 * LDA2];
    const int u = blockIdx.x;
    const int t = threadIdx.x;

    if (u >= 768) {
        // ---- one chunk of 256 edges -> atomicOr into (pre-zeroed) mask ----
        int e = (u - 768) * 256 + t;
        int src = ei[e];
        int dst = ei[NEDGE + e];
        atomicOr(&mask[src * MW + (dst >> 5)], 1u << (dst & 31));
        return;
    }

    // ---- one 64x64 QKV GEMM tile (bf16 MFMA, 4 waves 2x2) ----
    const int lane = t & 63, w = t >> 6;
    const int wm = w & 1, wn = w >> 1;
    const int ml = lane & 15, quad = lane >> 4;
    const int m0 = (u & 63) << 6;
    const int ysel = u >> 6;
    const int wsel = ysel >> 2;
    const float* W = (wsel == 0) ? Wq : ((wsel == 1) ? Wk : Wv);
    const int n0 = (ysel & 3) << 6;
    const int srow = t >> 3, scol = (t & 7) * 8;
    f32x4 acc[2][2];
    f32x4 zero = {0.f, 0.f, 0.f, 0.f};
    acc[0][0] = zero; acc[0][1] = zero; acc[1][0] = zero; acc[1][1] = zero;

    for (int k0 = 0; k0 < Hh; k0 += 64) {
        float4 a[2][2], bwt[2][2];
        #pragma unroll
        for (int s = 0; s < 2; ++s) {
            const float* ap = x + (size_t)(m0 + srow + s * 32) * Hh + k0 + scol;
            a[s][0] = *(const float4*)ap;
            a[s][1] = *(const float4*)(ap + 4);
            const float* bp = W + (size_t)(n0 + srow + s * 32) * Hh + k0 + scol;
            bwt[s][0] = *(const float4*)bp;
            bwt[s][1] = *(const float4*)(bp + 4);
        }
        __syncthreads();
        #pragma unroll
        for (int s = 0; s < 2; ++s) {
            bf16x8 av = {(bf16_t)a[s][0].x, (bf16_t)a[s][0].y, (bf16_t)a[s][0].z, (bf16_t)a[s][0].w,
                         (bf16_t)a[s][1].x, (bf16_t)a[s][1].y, (bf16_t)a[s][1].z, (bf16_t)a[s][1].w};
            bf16x8 bv = {(bf16_t)bwt[s][0].x, (bf16_t)bwt[s][0].y, (bf16_t)bwt[s][0].z, (bf16_t)bwt[s][0].w,
                         (bf16_t)bwt[s][1].x, (bf16_t)bwt[s][1].y, (bf16_t)bwt[s][1].z, (bf16_t)bwt[s][1].w};
            *(bf16x8*)&As[(srow + s * 32) * LDA2 + scol] = av;
            *(bf16x8*)&Ws[(srow + s * 32) * LDA2 + scol] = bv;
        }
        __syncthreads();
        #pragma unroll
        for (int kk = 0; kk < 64; kk += 32) {
            bf16x8 af[2], bfr[2];
            #pragma unroll
            for (int i = 0; i < 2; ++i) {
                af[i]  = *(const bf16x8*)&As[(wm * 32 + i * 16 + ml) * LDA2 + kk + quad * 8];
                bfr[i] = *(const bf16x8*)&Ws[(wn * 32 + i * 16 + ml) * LDA2 + kk + quad * 8];
            }
            #pragma unroll
            for (int i = 0; i < 2; ++i)
                #pragma unroll
                for (int j = 0; j < 2; ++j)
                    acc[i][j] = __builtin_amdgcn_mfma_f32_16x16x32_bf16(af[i], bfr[j], acc[i][j], 0, 0, 0);
        }
    }
    bf16_t* Ob16 = (wsel == 1) ? Kb16 : Vb16;
    #pragma unroll
    for (int i = 0; i < 2; ++i)
        #pragma unroll
        for (int j = 0; j < 2; ++j)
            #pragma unroll
            for (int r = 0; r < 4; ++r) {
                int mg = m0 + wm * 32 + i * 16 + quad * 4 + r;
                int ng = n0 + wn * 32 + j * 16 + ml;
                float v = acc[i][j][r];
                if (wsel == 0) Qb[(size_t)mg * Hh + ng] = v;
                else           Ob16[(size_t)mg * Hh + ng] = (bf16_t)v;
            }
}

// ===========================================================================
// K1: fused attention + out-projection + residual + LayerNorm.
// Block = 1024 threads = 16 waves; wave w owns global row g = bid*16 + w
// (b = g>>11, i = g&2047) and runs the attn7 in-register online-softmax loop
// (no barriers in the neighbor loop). The 16 finished rows form a full M=16
// bf16 A-tile in LDS; epilogue = proven out_ln GEMM (wave w computes the
// 16-col stripe w*16..w*16+15, 8 MFMA), then residual + LN (wave w = row w).
// Same k-summation order as out_ln -> bit-identical output.
// LDS: nbr[16][2112] (67.6 KB, aliased by ybuf later) + As 8.4 KB +
// Ws 36.9 KB = 112.9 KB -> 1 block/CU, 16 waves.
// ===========================================================================
__global__ __launch_bounds__(1024) void attn_out_ln_kernel(
    const float* __restrict__ Qb, const bf16_t* __restrict__ Kb16, const bf16_t* __restrict__ Vb16,
    const unsigned int* __restrict__ mask, const float* __restrict__ Wo,
    const float* __restrict__ x, const float* __restrict__ gamma, const float* __restrict__ beta,
    float* __restrict__ out)
{
    __shared__ __align__(16) char smem[16 * NBW * 2 + 16 * ALD * 2 + 256 * LDA2 * 2];
    unsigned short* nbr = (unsigned short*)smem;              // [16][NBW]
    float*  ybuf = (float*)smem;                              // [16][260], alias over nbr
    bf16_t* As   = (bf16_t*)(smem + 16 * NBW * 2);            // [16][ALD]
    bf16_t* Ws   = (bf16_t*)(smem + 16 * NBW * 2 + 16 * ALD * 2);  // [256][LDA2]

    const int t = threadIdx.x;
    const int w = t >> 6, lane = t & 63;
    const int ml = lane & 15, quad = lane >> 4;
    const int g = (blockIdx.x << 4) + w;     // global row 0..4095
    const int i = g & (Nn - 1);
    const int b = g >> 11;

    // ---- decode mask row i into this wave's neighbor list ----
    unsigned int bits = mask[i * MW + lane];
    int cnt = __popc(bits);
    int incl = cnt;
    #pragma unroll
    for (int off = 1; off < 64; off <<= 1) {
        int v = __shfl_up(incl, off, 64);
        if (lane >= off) incl += v;
    }
    int idx = incl - cnt;
    unsigned int bb = bits;
    while (bb) {
        int bit = __ffs(bb) - 1;
        nbr[w * NBW + idx++] = (unsigned short)(lane * 32 + bit);
        bb &= bb - 1;
    }
    int nn = __shfl(incl, 63, 64);
    if (lane == 63) nbr[w * NBW + idx] = 0;   // sentinel keeps prefetch addr valid
    __syncthreads();

    // ---- in-register online-softmax attention (attn7 loop) ----
    const int off4 = lane << 2;
    const float4 qv = *(const float4*)(Qb + (size_t)g * Hh + off4);
    const bf16_t* kb = Kb16 + ((size_t)b << 19);   // b * 2048 * 256
    const bf16_t* vb = Vb16 + ((size_t)b << 19);
    const float scale = 0.17677669529663687f;      // 1/sqrt(32)

    float m_run = -1e30f, l_run = 0.f;
    float o0 = 0.f, o1 = 0.f, o2 = 0.f, o3 = 0.f;
    if (nn > 0) {
        int j = nbr[w * NBW];
        bf16x4 kv = *(const bf16x4*)(kb + ((size_t)j << 8) + off4);
        bf16x4 vv = *(const bf16x4*)(vb + ((size_t)j << 8) + off4);
        for (int n = 0; n < nn; ++n) {
            int jn = nbr[w * NBW + n + 1];    // sentinel makes this always valid
            bf16x4 kn = *(const bf16x4*)(kb + ((size_t)jn << 8) + off4);
            bf16x4 vn = *(const bf16x4*)(vb + ((size_t)jn << 8) + off4);
            float p = fmaf((float)kv.x, qv.x, fmaf((float)kv.y, qv.y,
                      fmaf((float)kv.z, qv.z, (float)kv.w * qv.w)));
            p += __shfl_xor(p, 1, 64);
            p += __shfl_xor(p, 2, 64);
            p += __shfl_xor(p, 4, 64);   // 8-lane head group holds head dot
            p *= scale;
            float m_new = fmaxf(m_run, p);
            float alpha = __expf(m_run - m_new);
            float wgt   = __expf(p - m_new);
            l_run = fmaf(l_run, alpha, wgt);
            o0 = fmaf(o0, alpha, wgt * (float)vv.x);
            o1 = fmaf(o1, alpha, wgt * (float)vv.y);
            o2 = fmaf(o2, alpha, wgt * (float)vv.z);
            o3 = fmaf(o3, alpha, wgt * (float)vv.w);
            m_run = m_new;
            kv = kn; vv = vn;
        }
    }
    float linv = (l_run > 0.f) ? 1.f / l_run : 0.f;
    // wave w's row -> bf16 A-tile row w (same rounding point as old attnb path)
    bf16x4 arow = {(bf16_t)(o0 * linv), (bf16_t)(o1 * linv),
                   (bf16_t)(o2 * linv), (bf16_t)(o3 * linv)};
    *(bf16x4*)&As[w * ALD + off4] = arow;
    __syncthreads();   // all 16 A-rows + all nbr reads complete

    // ---- out-projection: C[16 x 256] = A[16 x 256] @ Wo^T, wave w -> cols w*16.. ----
    const int wrow = t >> 2, wcol = (t & 3) << 4;   // Ws staging: row 0..255, 16 cols
    f32x4 acc = {0.f, 0.f, 0.f, 0.f};
    for (int k0 = 0; k0 < Hh; k0 += 64) {
        const float* wp = Wo + (size_t)wrow * Hh + k0 + wcol;
        float4 w0 = ((const float4*)wp)[0];
        float4 w1 = ((const float4*)wp)[1];
        float4 w2 = ((const float4*)wp)[2];
        float4 w3 = ((const float4*)wp)[3];
        __syncthreads();   // previous iteration's MFMA reads of Ws done
        bf16x8 lo = {(bf16_t)w0.x, (bf16_t)w0.y, (bf16_t)w0.z, (bf16_t)w0.w,
                     (bf16_t)w1.x, (bf16_t)w1.y, (bf16_t)w1.z, (bf16_t)w1.w};
        bf16x8 hi = {(bf16_t)w2.x, (bf16_t)w2.y, (bf16_t)w2.z, (bf16_t)w2.w,
                     (bf16_t)w3.x, (bf16_t)w3.y, (bf16_t)w3.z, (bf16_t)w3.w};
        *(bf16x8*)&Ws[wrow * LDA2 + wcol] = lo;
        *(bf16x8*)&Ws[wrow * LDA2 + wcol + 8] = hi;
        __syncthreads();
        #pragma unroll
        for (int kk = 0; kk < 64; kk += 32) {
            bf16x8 af  = *(const bf16x8*)&As[ml * ALD + k0 + kk + quad * 8];
            bf16x8 bfr = *(const bf16x8*)&Ws[(w * 16 + ml) * LDA2 + kk + quad * 8];
            acc = __builtin_amdgcn_mfma_f32_16x16x32_bf16(af, bfr, acc, 0, 0, 0);
        }
    }
    // ---- y = C + x (residual) into ybuf (aliases nbr; attention fully done) ----
    #pragma unroll
    for (int r = 0; r < 4; ++r) {
        int row = quad * 4 + r;
        int col = (w << 4) + ml;
        ybuf[row * 260 + col] = acc[r] + x[(size_t)((blockIdx.x << 4) + row) * Hh + col];
    }
    __syncthreads();
    // ---- LayerNorm: wave w handles row w ----
    {
        float4 v = *(const float4*)&ybuf[w * 260 + off4];
        float sum = v.x + v.y + v.z + v.w;
        #pragma unroll
        for (int m = 1; m < 64; m <<= 1) sum += __shfl_xor(sum, m, 64);
        float mu = sum * (1.f / Hh);
        float4 d = {v.x - mu, v.y - mu, v.z - mu, v.w - mu};
        float ss = d.x * d.x + d.y * d.y + d.z * d.z + d.w * d.w;
        #pragma unroll
        for (int m = 1; m < 64; m <<= 1) ss += __shfl_xor(ss, m, 64);
        float r = rsqrtf(ss * (1.f / Hh) + LN_EPS);
        float4 gm = *(const float4*)(gamma + off4);
        float4 bt = *(const float4*)(beta + off4);
        float4 ov = {d.x * r * gm.x + bt.x, d.y * r * gm.y + bt.y,
                     d.z * r * gm.z + bt.z, d.w * r * gm.w + bt.w};
        *(float4*)(out + (size_t)g * Hh + off4) = ov;
    }
}

extern "C" void kernel_launch(void* const* d_in, const int* in_sizes, int n_in,
                              void* d_out, int out_size, void* d_ws, size_t ws_size,
                              hipStream_t stream) {
    const float* x     = (const float*)d_in[0];
    const int*   ei    = (const int*)d_in[1];
    // d_in[2] = edge_weights: unused by the reference
    const float* Wq    = (const float*)d_in[3];
    const float* Wk    = (const float*)d_in[4];
    const float* Wv    = (const float*)d_in[5];
    const float* Wo    = (const float*)d_in[6];
    const float* gamma = (const float*)d_in[7];
    const float* beta  = (const float*)d_in[8];
    float* out = (float*)d_out;

    const int NTOK = Bb * Nn * Hh;  // 1048576
    float*  Qb    = (float*)d_ws;
    bf16_t* Kb16  = (bf16_t*)(Qb + NTOK);
    bf16_t* Vb16  = Kb16 + NTOK;
    unsigned int* mask = (unsigned int*)(Vb16 + NTOK);

    hipMemsetAsync(mask, 0, Nn * MW * sizeof(unsigned int), stream);
    hipLaunchKernelGGL(prep_kernel, dim3(1024), dim3(256), 0, stream,
                       x, Wq, Wk, Wv, ei, Qb, Kb16, Vb16, mask);
    hipLaunchKernelGGL(attn_out_ln_kernel, dim3((Bb * Nn) / 16), dim3(1024), 0, stream,
                       Qb, Kb16, Vb16, mask, Wo, x, gamma, beta, out);
}